// Round 16
// baseline (345.041 us; speedup 1.0000x reference)
//
#include <hip/hip_runtime.h>
#include <hip/hip_bf16.h>
#include <math.h>

#define D_MODEL 1024
#define SEQ     1024
#define NHEADS  16
#define NKVH    4
#define HDIM    64
#define NEXP    64
#define TOPK    6
#define HEXP    512
#define EPS     1e-5f
#define MAXTILES 120   // 112 expert tiles max + 8 shared-expert tiles

typedef __attribute__((ext_vector_type(8))) short bf16x8;
typedef __attribute__((ext_vector_type(4))) float f32x4;

struct bfrag2 { bf16x8 hi, lo; };
struct f32x8r { float v[8]; };

__device__ __forceinline__ unsigned rne1(float a) {
  union { float f; unsigned u; } x; x.f = a;
  return (x.u + 0x7fffu + ((x.u >> 16) & 1u)) >> 16;
}
__device__ __forceinline__ float frombf(unsigned h) {
  union { float f; unsigned u; } x; x.u = h << 16; return x.f;
}
__device__ __forceinline__ void split_pack(float a, float b, unsigned& hi, unsigned& lo) {
  unsigned ha = rne1(a), hb = rne1(b);
  hi = ha | (hb << 16);
  lo = rne1(a - frombf(ha)) | (rne1(b - frombf(hb)) << 16);
}
__device__ __forceinline__ unsigned pk2bf(float a, float b) {
  return rne1(a) | (rne1(b) << 16);
}

__device__ __forceinline__ f32x4 mfma16(bf16x8 a, bf16x8 b, f32x4 c) {
  return __builtin_amdgcn_mfma_f32_16x16x32_bf16(a, b, c, 0, 0, 0);
}
__device__ __forceinline__ f32x4 mfma_sp(bf16x8 ah, bf16x8 al, const bfrag2& b, f32x4 c) {
  c = mfma16(ah, b.hi, c);
  c = mfma16(ah, b.lo, c);
  c = mfma16(al, b.hi, c);
  return c;
}

// barrier WITHOUT the compiler's vmcnt(0) drain: LDS ordered, global loads in flight
__device__ __forceinline__ void barrier_nv() {
  asm volatile("s_waitcnt lgkmcnt(0)" ::: "memory");
  __builtin_amdgcn_s_barrier();
}

__device__ __forceinline__ f32x8r loadraw8(const float* __restrict__ p, int ld) {
  f32x8r r;
#pragma unroll
  for (int i = 0; i < 8; i++) r.v[i] = p[(size_t)ld * i];
  return r;
}
__device__ __forceinline__ bfrag2 cvt_bf2(const f32x8r& f) {
  union { bf16x8 v; unsigned u[4]; } H, L;
  split_pack(f.v[0], f.v[1], H.u[0], L.u[0]);
  split_pack(f.v[2], f.v[3], H.u[1], L.u[1]);
  split_pack(f.v[4], f.v[5], H.u[2], L.u[2]);
  split_pack(f.v[6], f.v[7], H.u[3], L.u[3]);
  bfrag2 r; r.hi = H.v; r.lo = L.v; return r;
}
__device__ __forceinline__ bf16x8 cvt_bf(const f32x8r& f) {
  union { bf16x8 v; unsigned u[4]; } r;
  r.u[0] = pk2bf(f.v[0], f.v[1]); r.u[1] = pk2bf(f.v[2], f.v[3]);
  r.u[2] = pk2bf(f.v[4], f.v[5]); r.u[3] = pk2bf(f.v[6], f.v[7]);
  return r.v;
}
template<int RL>
__device__ __forceinline__ bf16x8 bfrag_lds(const ushort* __restrict__ B, int akb, int c) {
  union { bf16x8 v; ushort s[8]; } r;
#pragma unroll
  for (int j = 0; j < 8; j++) r.s[j] = B[(akb + j) * RL + c];
  return r.v;
}

// ---------------- rmsnorm over D=1024 (+ optional bf16 copy) ----------------
__global__ __launch_bounds__(256) void rmsnorm_k(const float* __restrict__ x,
    const float* __restrict__ w, float* __restrict__ out, ushort* __restrict__ outb) {
  int t = blockIdx.x;
  const float4* xr = (const float4*)(x + (size_t)t * D_MODEL);
  float4 v = xr[threadIdx.x];
  float ss = v.x*v.x + v.y*v.y + v.z*v.z + v.w*v.w;
  for (int off = 32; off; off >>= 1) ss += __shfl_xor(ss, off);
  __shared__ float red[4];
  if ((threadIdx.x & 63) == 0) red[threadIdx.x >> 6] = ss;
  __syncthreads();
  float tot = red[0] + red[1] + red[2] + red[3];
  float inv = rsqrtf(tot * (1.f / D_MODEL) + EPS);
  float4 wv = ((const float4*)w)[threadIdx.x];
  float4 o;
  o.x = v.x * inv * wv.x; o.y = v.y * inv * wv.y;
  o.z = v.z * inv * wv.z; o.w = v.w * inv * wv.w;
  ((float4*)(out + (size_t)t * D_MODEL))[threadIdx.x] = o;
  if (outb) {
    uint2 b;
    b.x = pk2bf(o.x, o.y); b.y = pk2bf(o.z, o.w);
    *(uint2*)(outb + (size_t)t * D_MODEL + threadIdx.x * 4) = b;
  }
}

// ---------------- fused QKV GEMM, plain bf16 inputs, f32 outputs -------------------
// grid = (12, 64): x<8 -> wq cols, 8..9 -> wk, 10..11 -> wv. K=1024 fixed.
__global__ __launch_bounds__(256) void mfma_gemm_qkv(const float* __restrict__ A,
    const float* __restrict__ WQ, const float* __restrict__ WK,
    const float* __restrict__ WV, float* __restrict__ Q, float* __restrict__ Kb,
    float* __restrict__ V) {
  const float* B; float* C; int N, bn;
  int bx = blockIdx.x;
  if (bx < 8)       { B = WQ; C = Q;  N = 1024; bn = bx << 7; }
  else if (bx < 10) { B = WK; C = Kb; N = 256;  bn = (bx - 8) << 7; }
  else              { B = WV; C = V;  N = 256;  bn = (bx - 10) << 7; }
  const int K = 1024;
  __shared__ short Ah[2][16][40];
  int bm = blockIdx.y << 4;
  int tid = threadIdx.x, wv = tid >> 6, lane = tid & 63;
  int m_ = tid >> 4, k_ = (tid & 15) << 1;
  int arow = lane & 15, akb = (lane >> 4) << 3;
  int c0 = bn + wv * 32 + arow;
  const float* ar = A + (size_t)(bm + m_) * K + k_;
  {
    float2 a0 = *(const float2*)ar;
    *(unsigned*)&Ah[0][m_][k_] = pk2bf(a0.x, a0.y);
  }
  float2 aO = *(const float2*)(ar + 32);
  float2 aE;
  f32x8r bE0 = loadraw8(B + (size_t)akb * N + c0, N);
  f32x8r bE1 = loadraw8(B + (size_t)akb * N + c0 + 16, N);
  f32x8r bO0 = loadraw8(B + (size_t)(32 + akb) * N + c0, N);
  f32x8r bO1 = loadraw8(B + (size_t)(32 + akb) * N + c0 + 16, N);
  __syncthreads();
  f32x4 acc0 = {0.f,0.f,0.f,0.f}, acc1 = {0.f,0.f,0.f,0.f};
  for (int k0 = 0; k0 < K; k0 += 64) {
    { // even
      int kp = (k0 + 64 < K) ? k0 + 64 : 0;
      f32x8r n0 = loadraw8(B + (size_t)(kp + akb) * N + c0, N);
      f32x8r n1 = loadraw8(B + (size_t)(kp + akb) * N + c0 + 16, N);
      float2 an = *(const float2*)(ar + kp);
      bf16x8 f0 = cvt_bf(bE0), f1 = cvt_bf(bE1);
      bf16x8 ah = *(const bf16x8*)&Ah[0][arow][akb];
      acc0 = mfma16(ah, f0, acc0);
      acc1 = mfma16(ah, f1, acc1);
      *(unsigned*)&Ah[1][m_][k_] = pk2bf(aO.x, aO.y);
      barrier_nv();
      bE0 = n0; bE1 = n1; aE = an;
    }
    { // odd
      int kp = (k0 + 96 < K) ? k0 + 96 : 0;
      f32x8r n0 = loadraw8(B + (size_t)(kp + akb) * N + c0, N);
      f32x8r n1 = loadraw8(B + (size_t)(kp + akb) * N + c0 + 16, N);
      float2 an = *(const float2*)(ar + kp);
      bf16x8 f0 = cvt_bf(bO0), f1 = cvt_bf(bO1);
      bf16x8 ah = *(const bf16x8*)&Ah[1][arow][akb];
      acc0 = mfma16(ah, f0, acc0);
      acc1 = mfma16(ah, f1, acc1);
      *(unsigned*)&Ah[0][m_][k_] = pk2bf(aE.x, aE.y);
      barrier_nv();
      bO0 = n0; bO1 = n1; aO = an;
    }
  }
  int r0 = (lane >> 4) << 2;
#pragma unroll
  for (int ri = 0; ri < 4; ri++) {
    size_t o0 = (size_t)(bm + r0 + ri) * N + c0;
    C[o0] = acc0[ri];
    C[o0 + 16] = acc1[ri];
  }
}

// ---------------- dense split-bf16 MFMA GEMM (wo), depth-2, relaxed barrier --------
__global__ __launch_bounds__(256) void mfma_gemm_k(const float* __restrict__ A,
    const float* __restrict__ B, float* __restrict__ C, float* __restrict__ C2,
    const float* __restrict__ resid, int N, int K) {
  __shared__ short Ah[2][16][40];
  __shared__ short Al[2][16][40];
  int bm = blockIdx.y << 4, bn = blockIdx.x << 7;
  int tid = threadIdx.x, wv = tid >> 6, lane = tid & 63;
  int m_ = tid >> 4, k_ = (tid & 15) << 1;
  int arow = lane & 15, akb = (lane >> 4) << 3;
  int c0 = bn + wv * 32 + arow;
  const float* ar = A + (size_t)(bm + m_) * K + k_;
  {
    float2 a0 = *(const float2*)ar;
    unsigned hi, lo; split_pack(a0.x, a0.y, hi, lo);
    *(unsigned*)&Ah[0][m_][k_] = hi;
    *(unsigned*)&Al[0][m_][k_] = lo;
  }
  float2 aO = *(const float2*)(ar + 32);
  float2 aE;
  f32x8r bE0 = loadraw8(B + (size_t)akb * N + c0, N);
  f32x8r bE1 = loadraw8(B + (size_t)akb * N + c0 + 16, N);
  f32x8r bO0 = loadraw8(B + (size_t)(32 + akb) * N + c0, N);
  f32x8r bO1 = loadraw8(B + (size_t)(32 + akb) * N + c0 + 16, N);
  __syncthreads();
  f32x4 acc0 = {0.f,0.f,0.f,0.f}, acc1 = {0.f,0.f,0.f,0.f};
  for (int k0 = 0; k0 < K; k0 += 64) {
    {
      int kp = (k0 + 64 < K) ? k0 + 64 : 0;
      f32x8r n0 = loadraw8(B + (size_t)(kp + akb) * N + c0, N);
      f32x8r n1 = loadraw8(B + (size_t)(kp + akb) * N + c0 + 16, N);
      float2 an = *(const float2*)(ar + kp);
      bfrag2 f0 = cvt_bf2(bE0), f1 = cvt_bf2(bE1);
      bf16x8 ah = *(const bf16x8*)&Ah[0][arow][akb];
      bf16x8 al = *(const bf16x8*)&Al[0][arow][akb];
      acc0 = mfma_sp(ah, al, f0, acc0);
      acc1 = mfma_sp(ah, al, f1, acc1);
      unsigned hi, lo; split_pack(aO.x, aO.y, hi, lo);
      *(unsigned*)&Ah[1][m_][k_] = hi;
      *(unsigned*)&Al[1][m_][k_] = lo;
      barrier_nv();
      bE0 = n0; bE1 = n1; aE = an;
    }
    {
      int kp = (k0 + 96 < K) ? k0 + 96 : 0;
      f32x8r n0 = loadraw8(B + (size_t)(kp + akb) * N + c0, N);
      f32x8r n1 = loadraw8(B + (size_t)(kp + akb) * N + c0 + 16, N);
      float2 an = *(const float2*)(ar + kp);
      bfrag2 f0 = cvt_bf2(bO0), f1 = cvt_bf2(bO1);
      bf16x8 ah = *(const bf16x8*)&Ah[1][arow][akb];
      bf16x8 al = *(const bf16x8*)&Al[1][arow][akb];
      acc0 = mfma_sp(ah, al, f0, acc0);
      acc1 = mfma_sp(ah, al, f1, acc1);
      unsigned hi, lo; split_pack(aE.x, aE.y, hi, lo);
      *(unsigned*)&Ah[0][m_][k_] = hi;
      *(unsigned*)&Al[0][m_][k_] = lo;
      barrier_nv();
      bO0 = n0; bO1 = n1; aO = an;
    }
  }
  int r0 = (lane >> 4) << 2;
#pragma unroll
  for (int ri = 0; ri < 4; ri++) {
    int row = bm + r0 + ri;
    size_t o0 = (size_t)row * N + c0;
    float v0 = acc0[ri], v1 = acc1[ri];
    if (resid) { v0 += resid[o0]; v1 += resid[o0 + 16]; }
    C[o0] = v0; C[o0 + 16] = v1;
    if (C2) { C2[o0] = v0; C2[o0 + 16] = v1; }
  }
}

// ---------------- causal flash attention, fused q/k rmsnorm + RoPE (f32 in) --------
// grid = (SEQ/64, NHEADS), 256 thr (4 waves); block = 1 head x 64 q-rows.
__global__ __launch_bounds__(256) void attn_fused(const float* __restrict__ qb,
    const float* __restrict__ kb, const float* __restrict__ vb,
    const float* __restrict__ qnw, const float* __restrict__ knw,
    const float* __restrict__ fcos, const float* __restrict__ fsin,
    float* __restrict__ ob) {
  int h = blockIdx.y;
  int qbase = ((SEQ / 64 - 1) - blockIdx.x) << 6;   // heaviest first
  int kvh = h >> 2;
  int tid = threadIdx.x, wv = tid >> 6, lane = tid & 63;
  __shared__ short Kt[64][72];
  __shared__ short Vt[64][72];
  __shared__ short Pl[4][16][72];
  int arow = lane & 15;
  int akb = (lane >> 4) << 3;
  int kg = lane >> 4;
  int qrow_base = qbase + wv * 16;
  // ---- Q load (f32) + per-head rmsnorm + rope, round once to bf16 ----
  bf16x8 qf[2];
  {
    int trow = qrow_base + arow;
    const float* qp = qb + (size_t)trow * (NHEADS*HDIM) + h * HDIM;
    float qv[16];
    float ss = 0.f;
#pragma unroll
    for (int c = 0; c < 2; c++) {
      float4 a = *(const float4*)(qp + akb + c * 32);
      float4 b = *(const float4*)(qp + akb + c * 32 + 4);
      qv[c*8+0]=a.x; qv[c*8+1]=a.y; qv[c*8+2]=a.z; qv[c*8+3]=a.w;
      qv[c*8+4]=b.x; qv[c*8+5]=b.y; qv[c*8+6]=b.z; qv[c*8+7]=b.w;
#pragma unroll
      for (int j = 0; j < 8; j++) ss += qv[c*8+j]*qv[c*8+j];
    }
    ss += __shfl_xor(ss, 16);
    ss += __shfl_xor(ss, 32);
    float inv = rsqrtf(ss * (1.f / HDIM) + EPS);
#pragma unroll
    for (int c = 0; c < 2; c++) {
      union { bf16x8 v; unsigned u[4]; } r;
#pragma unroll
      for (int j2 = 0; j2 < 4; j2++) {
        int d = akb + c * 32 + 2 * j2;
        float c_ = fcos[trow * 32 + (d >> 1)], s_ = fsin[trow * 32 + (d >> 1)];
        float x0 = qv[c*8 + 2*j2]     * inv * qnw[d];
        float x1 = qv[c*8 + 2*j2 + 1] * inv * qnw[d + 1];
        r.u[j2] = pk2bf(x0 * c_ - x1 * s_, x0 * s_ + x1 * c_);
      }
      qf[c] = r.v;
    }
  }
  f32x4 accO[4];
  float m_[4], l_[4];
#pragma unroll
  for (int n = 0; n < 4; n++) { accO[n] = (f32x4){0.f,0.f,0.f,0.f}; m_[n] = -1e30f; l_[n] = 0.f; }
  int ntiles = (qbase >> 6) + 1;
  for (int ti = 0; ti < ntiles; ti++) {
    int ts = ti << 6;
    // ---- stage K (norm+rope fused, f32 in) and V (transposed) ----
#pragma unroll
    for (int i = 0; i < 2; i++) {
      int f = tid + i * 256;          // chunk id in [0,512): 8 f32 per chunk
      int kk = f >> 3, d8 = (f & 7) << 3;
      size_t src = (size_t)(ts + kk) * (NKVH*HDIM) + kvh * HDIM + d8;
      float4 k0 = *(const float4*)(kb + src);
      float4 k1 = *(const float4*)(kb + src + 4);
      float4 v0 = *(const float4*)(vb + src);
      float4 v1 = *(const float4*)(vb + src + 4);
      float kf[8] = {k0.x,k0.y,k0.z,k0.w,k1.x,k1.y,k1.z,k1.w};
      float ss = 0.f;
#pragma unroll
      for (int j = 0; j < 8; j++) ss += kf[j]*kf[j];
      ss += __shfl_xor(ss, 1);
      ss += __shfl_xor(ss, 2);
      ss += __shfl_xor(ss, 4);
      float inv = rsqrtf(ss * (1.f / HDIM) + EPS);
      int t_ = ts + kk;
      union { uint4 u; unsigned w[4]; } ko;
#pragma unroll
      for (int j2 = 0; j2 < 4; j2++) {
        int d = d8 + 2 * j2;
        float c_ = fcos[t_ * 32 + (d >> 1)], s_ = fsin[t_ * 32 + (d >> 1)];
        float x0 = kf[2*j2]     * inv * knw[d];
        float x1 = kf[2*j2 + 1] * inv * knw[d + 1];
        ko.w[j2] = pk2bf(x0 * c_ - x1 * s_, x0 * s_ + x1 * c_);
      }
      *(uint4*)&Kt[kk][d8] = ko.u;
      Vt[d8 + 0][kk] = (short)rne1(v0.x);
      Vt[d8 + 1][kk] = (short)rne1(v0.y);
      Vt[d8 + 2][kk] = (short)rne1(v0.z);
      Vt[d8 + 3][kk] = (short)rne1(v0.w);
      Vt[d8 + 4][kk] = (short)rne1(v1.x);
      Vt[d8 + 5][kk] = (short)rne1(v1.y);
      Vt[d8 + 6][kk] = (short)rne1(v1.z);
      Vt[d8 + 7][kk] = (short)rne1(v1.w);
    }
    __syncthreads();
    f32x4 accS[4];
#pragma unroll
    for (int n = 0; n < 4; n++) accS[n] = (f32x4){0.f,0.f,0.f,0.f};
#pragma unroll
    for (int c = 0; c < 2; c++) {
#pragma unroll
      for (int n = 0; n < 4; n++) {
        bf16x8 bf = *(const bf16x8*)&Kt[n*16 + arow][c*32 + akb];
        accS[n] = mfma16(qf[c], bf, accS[n]);
      }
    }
#pragma unroll
    for (int ri = 0; ri < 4; ri++) {
      int qrow = qrow_base + kg*4 + ri;
      float mx = -1e30f;
#pragma unroll
      for (int n = 0; n < 4; n++) {
        int key = ts + n*16 + arow;
        float s = (key <= qrow) ? accS[n][ri] * 0.125f : -1e30f;
        accS[n][ri] = s;
        mx = fmaxf(mx, s);
      }
      for (int off = 1; off < 16; off <<= 1) mx = fmaxf(mx, __shfl_xor(mx, off));
      float mn = fmaxf(m_[ri], mx);
      float a = __expf(m_[ri] - mn);
      float sum = 0.f;
#pragma unroll
      for (int n = 0; n < 4; n++) {
        float p = __expf(accS[n][ri] - mn);
        accS[n][ri] = p;
        sum += p;
      }
      for (int off = 1; off < 16; off <<= 1) sum += __shfl_xor(sum, off);
      l_[ri] = l_[ri] * a + sum;
      m_[ri] = mn;
#pragma unroll
      for (int n = 0; n < 4; n++) accO[n][ri] *= a;
    }
#pragma unroll
    for (int ri = 0; ri < 4; ri++)
#pragma unroll
      for (int n = 0; n < 4; n++)
        Pl[wv][kg*4 + ri][n*16 + arow] = (short)rne1(accS[n][ri]);
#pragma unroll
    for (int c = 0; c < 2; c++) {
      bf16x8 pf = *(const bf16x8*)&Pl[wv][arow][c*32 + akb];
#pragma unroll
      for (int n = 0; n < 4; n++) {
        bf16x8 vf = *(const bf16x8*)&Vt[n*16 + arow][c*32 + akb];
        accO[n] = mfma16(pf, vf, accO[n]);
      }
    }
    __syncthreads();
  }
#pragma unroll
  for (int ri = 0; ri < 4; ri++) {
    int qrow = qrow_base + kg*4 + ri;
    float inv = 1.f / l_[ri];
#pragma unroll
    for (int n = 0; n < 4; n++)
      ob[(size_t)qrow * (NHEADS*HDIM) + h * HDIM + n*16 + arow] = accO[n][ri] * inv;
  }
}

// ---------------- gate: softmax -> top-6 (low-index tie-break) ----------------
__global__ __launch_bounds__(64) void gate_topk_k(const float* __restrict__ z,
    const float* __restrict__ gw, int* __restrict__ sel, float* __restrict__ topw,
    int* __restrict__ counts) {
  int t = blockIdx.x, lane = threadIdx.x;
  const float* zr = z + (size_t)t * D_MODEL;
  float acc = 0.f;
  for (int d = 0; d < D_MODEL; d += 4) {
    float4 zv = *(const float4*)(zr + d);
    acc += zv.x * gw[(size_t)(d + 0) * NEXP + lane];
    acc += zv.y * gw[(size_t)(d + 1) * NEXP + lane];
    acc += zv.z * gw[(size_t)(d + 2) * NEXP + lane];
    acc += zv.w * gw[(size_t)(d + 3) * NEXP + lane];
  }
  float m = acc;
  for (int off = 32; off; off >>= 1) m = fmaxf(m, __shfl_xor(m, off));
  float p = __expf(acc - m);
  float s = p;
  for (int off = 32; off; off >>= 1) s += __shfl_xor(s, off);
  p /= s;
  float rem = p, wsum = 0.f;
  float wvv[TOPK]; int wi[TOPK];
  for (int i = 0; i < TOPK; i++) {
    float v = rem; int idx = lane;
    for (int off = 32; off; off >>= 1) {
      float v2 = __shfl_xor(v, off);
      int i2 = __shfl_xor(idx, off);
      if (v2 > v || (v2 == v && i2 < idx)) { v = v2; idx = i2; }
    }
    wvv[i] = v; wi[i] = idx; wsum += v;
    if (lane == idx) rem = -1.f;
  }
  if (lane < TOPK) {
    sel[t * TOPK + lane] = wi[lane];
    topw[t * TOPK + lane] = wvv[lane] / wsum;
  }
  if (lane == 0)
    for (int i = 0; i < TOPK; i++) atomicAdd(&counts[wi[i]], 1);
}

// ---------------- scan + flattened (expert, mtile) work list (+shared tiles) -------
__global__ void scan_k(const int* __restrict__ counts, int* __restrict__ offs,
                       int* __restrict__ cursor, int* __restrict__ tile2e,
                       int* __restrict__ tile2mt, int* __restrict__ ntiles) {
  int lane = threadIdx.x;
  int c = counts[lane];
  int x = c;
  for (int off = 1; off < 64; off <<= 1) {
    int y = __shfl_up(x, off);
    if (lane >= off) x += y;
  }
  offs[lane] = x - c;
  cursor[lane] = x - c;
  int nt = (c + 127) >> 7;
  int y = nt;
  for (int off = 1; off < 64; off <<= 1) {
    int t2 = __shfl_up(y, off);
    if (lane >= off) y += t2;
  }
  int tbase = y - nt;
  for (int i = 0; i < nt; i++) { tile2e[tbase + i] = lane; tile2mt[tbase + i] = i; }
  if (lane == 63) {
    for (int i = 0; i < 8; i++) { tile2e[y + i] = NEXP; tile2mt[y + i] = i; }
    ntiles[0] = y + 8;
  }
}

__global__ void scatter_k(const int* __restrict__ sel, const float* __restrict__ topw,
    int* __restrict__ cursor, int* __restrict__ tok, float* __restrict__ wt) {
  int t = blockIdx.x * 256 + threadIdx.x;
  if (t >= SEQ) return;
  for (int i = 0; i < TOPK; i++) {
    int e = sel[t * TOPK + i];
    int pos = atomicAdd(&cursor[e], 1);
    tok[pos] = t;
    wt[pos] = topw[t * TOPK + i];
  }
}

// ---------------- MoE phase A (r8): coalesced-LDS B, relaxed barrier, dbuf ---------
__global__ __launch_bounds__(256) void moe_up6(const ushort* __restrict__ zb,
    const float* __restrict__ w1, const float* __restrict__ w3, size_t wstride,
    const float* __restrict__ sw1, const float* __restrict__ sw3,
    ushort* __restrict__ g, ushort* __restrict__ sg,
    const int* __restrict__ tok_list, const float* __restrict__ wt_list,
    const int* __restrict__ counts, const int* __restrict__ offs,
    const int* __restrict__ tile2e, const int* __restrict__ tile2mt,
    const int* __restrict__ ntiles) {
  int gt = blockIdx.y;
  if (gt >= ntiles[0]) return;
  int e = tile2e[gt];
  int mt = tile2mt[gt] << 7;
  bool sh = (e == NEXP);
  int cnt = sh ? SEQ : counts[e];
  int off = sh ? 0 : offs[e];
  const float* w1p = (sh ? sw1 : w1 + (size_t)e * wstride) + (blockIdx.x << 6);
  const float* w3p = (sh ? sw3 : w3 + (size_t)e * wstride) + (blockIdx.x << 6);
  ushort* gout = sh ? sg : g;
  __shared__ ushort Ah[2][128][40];
  __shared__ ushort Bs[2][2][32][74];
  __shared__ int toks[128];
  int tid = threadIdx.x, wv = tid >> 6, lane = tid & 63;
  int arow = lane & 15, akb = (lane >> 4) << 3, kg = lane >> 4;
  int c0l = wv * 16 + arow;
  int c0 = (blockIdx.x << 6) + c0l;
  if (tid < 128) {
    int r = mt + tid; if (r >= cnt) r = cnt - 1;
    toks[tid] = sh ? r : tok_list[off + r];
  }
  __syncthreads();
  int row0 = tid >> 2, q8 = (tid & 3) << 3, row1 = row0 + 64;
  const ushort* zr0 = zb + (size_t)toks[row0] * D_MODEL + q8;
  const ushort* zr1 = zb + (size_t)toks[row1] * D_MODEL + q8;
  int kB = tid >> 4, cB = (tid & 15) << 2;
  const float* w1q = w1p + (size_t)kB * HEXP + cB;
  const float* w3q = w3p + (size_t)kB * HEXP + cB;
  uint4  ra0 = *(const uint4*)zr0;
  uint4  ra1 = *(const uint4*)zr1;
  float4 rb1a = *(const float4*)w1q;
  float4 rb1b = *(const float4*)(w1q + 16 * HEXP);
  float4 rb3a = *(const float4*)w3q;
  float4 rb3b = *(const float4*)(w3q + 16 * HEXP);
  f32x4 a1[8], a3[8];
#pragma unroll
  for (int f = 0; f < 8; f++) { a1[f] = (f32x4){0.f,0.f,0.f,0.f}; a3[f] = (f32x4){0.f,0.f,0.f,0.f}; }
  int cur = 0;
  for (int k0 = 0; k0 < D_MODEL; k0 += 32) {
    int kp = (k0 + 32 < D_MODEL) ? k0 + 32 : 0;
    uint4  na0 = *(const uint4*)(zr0 + kp);
    uint4  na1 = *(const uint4*)(zr1 + kp);
    const float* w1n = w1q + (size_t)kp * HEXP;
    const float* w3n = w3q + (size_t)kp * HEXP;
    float4 nb1a = *(const float4*)w1n;
    float4 nb1b = *(const float4*)(w1n + 16 * HEXP);
    float4 nb3a = *(const float4*)w3n;
    float4 nb3b = *(const float4*)(w3n + 16 * HEXP);
    *(uint4*)&Ah[cur][row0][q8] = ra0;
    *(uint4*)&Ah[cur][row1][q8] = ra1;
    {
      unsigned* p = (unsigned*)&Bs[cur][0][kB][cB];
      p[0] = pk2bf(rb1a.x, rb1a.y); p[1] = pk2bf(rb1a.z, rb1a.w);
      unsigned* p2 = (unsigned*)&Bs[cur][0][kB + 16][cB];
      p2[0] = pk2bf(rb1b.x, rb1b.y); p2[1] = pk2bf(rb1b.z, rb1b.w);
      unsigned* p3 = (unsigned*)&Bs[cur][1][kB][cB];
      p3[0] = pk2bf(rb3a.x, rb3a.y); p3[1] = pk2bf(rb3a.z, rb3a.w);
      unsigned* p4 = (unsigned*)&Bs[cur][1][kB + 16][cB];
      p4[0] = pk2bf(rb3b.x, rb3b.y); p4[1] = pk2bf(rb3b.z, rb3b.w);
    }
    barrier_nv();
    bf16x8 f1 = bfrag_lds<74>(&Bs[cur][0][0][0], akb, c0l);
    bf16x8 f3 = bfrag_lds<74>(&Bs[cur][1][0][0], akb, c0l);
#pragma unroll
    for (int f = 0; f < 8; f++) {
      bf16x8 ah = *(const bf16x8*)&Ah[cur][f*16 + arow][akb];
      a1[f] = mfma16(ah, f1, a1[f]);
      a3[f] = mfma16(ah, f3, a3[f]);
    }
    ra0 = na0; ra1 = na1;
    rb1a = nb1a; rb1b = nb1b; rb3a = nb3a; rb3b = nb3b;
    cur ^= 1;
  }
#pragma unroll
  for (int f = 0; f < 8; f++)
#pragma unroll
    for (int ri = 0; ri < 4; ri++) {
      int r = mt + f*16 + kg*4 + ri;
      if (r < cnt) {
        float wt = sh ? 1.0f : wt_list[off + r];
        float h1 = a1[f][ri], h3 = a3[f][ri];
        float gv = h1 / (1.f + __expf(-h1)) * h3 * wt;
        gout[(size_t)(off + r) * HEXP + c0] = (ushort)rne1(gv);
      }
    }
}

// ---------------- MoE phase B (r8): coalesced-LDS B, relaxed barrier, dbuf ---------
__global__ __launch_bounds__(256) void moe_down6(const ushort* __restrict__ g,
    const ushort* __restrict__ sg, const float* __restrict__ w2, size_t wstride,
    const float* __restrict__ sw2, float* __restrict__ out,
    const int* __restrict__ tok_list, const int* __restrict__ counts,
    const int* __restrict__ offs, const int* __restrict__ tile2e,
    const int* __restrict__ tile2mt, const int* __restrict__ ntiles) {
  int gt = blockIdx.y;
  if (gt >= ntiles[0]) return;
  int e = tile2e[gt];
  int mt = tile2mt[gt] << 7;
  bool sh = (e == NEXP);
  int cnt = sh ? SEQ : counts[e];
  int off = sh ? 0 : offs[e];
  const float* w2p = (sh ? sw2 : w2 + (size_t)e * wstride) + (blockIdx.x << 7);
  const ushort* gin = sh ? sg : g;
  __shared__ ushort Ah[2][128][40];
  __shared__ ushort Bs[2][32][138];
  int tid = threadIdx.x, wv = tid >> 6, lane = tid & 63;
  int arow = lane & 15, akb = (lane >> 4) << 3, kg = lane >> 4;
  int c0l = wv * 32 + arow;
  int c0 = (blockIdx.x << 7) + c0l;
  int row0 = tid >> 2, q8 = (tid & 3) << 3, row1 = row0 + 64;
  int rr0 = mt + row0; if (rr0 >= cnt) rr0 = cnt - 1;
  int rr1 = mt + row1; if (rr1 >= cnt) rr1 = cnt - 1;
  const ushort* gr0 = gin + (size_t)(off + rr0) * HEXP + q8;
  const ushort* gr1 = gin + (size_t)(off + rr1) * HEXP + q8;
  int kB = tid >> 3, cB = (tid & 7) << 4;
  const float* w2q = w2p + (size_t)kB * D_MODEL + cB;
  uint4  ra0 = *(const uint4*)gr0;
  uint4  ra1 = *(const uint4*)gr1;
  float4 rb0 = *(const float4*)(w2q);
  float4 rb1 = *(const float4*)(w2q + 4);
  float4 rb2 = *(const float4*)(w2q + 8);
  float4 rb3 = *(const float4*)(w2q + 12);
  f32x4 ac0[8], ac1[8];
#pragma unroll
  for (int f = 0; f < 8; f++) { ac0[f] = (f32x4){0.f,0.f,0.f,0.f}; ac1[f] = (f32x4){0.f,0.f,0.f,0.f}; }
  int cur = 0;
  for (int k0 = 0; k0 < HEXP; k0 += 32) {
    int kp = (k0 + 32 < HEXP) ? k0 + 32 : 0;
    uint4  na0 = *(const uint4*)(gr0 + kp);
    uint4  na1 = *(const uint4*)(gr1 + kp);
    const float* wn = w2q + (size_t)kp * D_MODEL;
    float4 nb0 = *(const float4*)(wn);
    float4 nb1 = *(const float4*)(wn + 4);
    float4 nb2 = *(const float4*)(wn + 8);
    float4 nb3 = *(const float4*)(wn + 12);
    *(uint4*)&Ah[cur][row0][q8] = ra0;
    *(uint4*)&Ah[cur][row1][q8] = ra1;
    {
      unsigned* p = (unsigned*)&Bs[cur][kB][cB];
      p[0] = pk2bf(rb0.x, rb0.y); p[1] = pk2bf(rb0.z, rb0.w);
      p[2] = pk2bf(rb1.x, rb1.y); p[3] = pk2bf(rb1.z, rb1.w);
      p[4] = pk2bf(rb2.x, rb2.y); p[5] = pk2bf(rb2.z, rb2.w);
      p[6] = pk2bf(rb3.x, rb3.y); p[7] = pk2bf(rb3.z, rb3.w);
    }
    barrier_nv();
    bf16x8 f0 = bfrag_lds<138>(&Bs[cur][0][0], akb, c0l);
    bf16x8 f1 = bfrag_lds<138>(&Bs[cur][0][0], akb, c0l + 16);
#pragma unroll
    for (int f = 0; f < 8; f++) {
      bf16x8 ah = *(const bf16x8*)&Ah[cur][f*16 + arow][akb];
      ac0[f] = mfma16(ah, f0, ac0[f]);
      ac1[f] = mfma16(ah, f1, ac1[f]);
    }
    ra0 = na0; ra1 = na1;
    rb0 = nb0; rb1 = nb1; rb2 = nb2; rb3 = nb3;
    cur ^= 1;
  }
#pragma unroll
  for (int f = 0; f < 8; f++)
#pragma unroll
    for (int ri = 0; ri < 4; ri++) {
      int r = mt + f*16 + kg*4 + ri;
      if (r < cnt) {
        int tok = sh ? r : tok_list[off + r];
        float* op = out + (size_t)tok * D_MODEL + c0;
        atomicAdd(op, ac0[f][ri]);
        atomicAdd(op + 16, ac1[f][ri]);
      }
    }
}

// ---------------- host ----------------
extern "C" void kernel_launch(void* const* d_in, const int* in_sizes, int n_in,
                              void* d_out, int out_size, void* d_ws, size_t ws_size,
                              hipStream_t stream) {
  const float* x     = (const float*)d_in[0];
  const float* fcos  = (const float*)d_in[1];
  const float* fsin  = (const float*)d_in[2];
  const float* anw   = (const float*)d_in[3];
  const float* fnw   = (const float*)d_in[4];
  const float* wq    = (const float*)d_in[5];
  const float* wk    = (const float*)d_in[6];
  const float* wvv   = (const float*)d_in[7];
  const float* wo    = (const float*)d_in[8];
  const float* qnw   = (const float*)d_in[9];
  const float* knw   = (const float*)d_in[10];
  const float* gatew = (const float*)d_in[11];
  const float* w1e   = (const float*)d_in[12];
  const float* w3e   = (const float*)d_in[13];
  const float* w2e   = (const float*)d_in[14];
  const float* sw1   = (const float*)d_in[15];
  const float* sw3   = (const float*)d_in[16];
  const float* sw2   = (const float*)d_in[17];
  float* out = (float*)d_out;

  char* ws = (char*)d_ws;
  const size_t MB = 1ull << 20;
  float*  hx    = (float*)(ws);             // 0-4MB (attn-norm out, then attn out)
  float*  h     = (float*)(ws + 4*MB);      // 4-8MB residual after attention
  float*  z     = (float*)(ws + 8*MB);      // 8-12MB ffn-norm out (f32, for gate)
  float*  qbuf  = (float*)(ws + 12*MB);     // 12-16MB f32 Q (dead after attn)
  float*  kbuf  = (float*)(ws + 16*MB);     // 1MB f32 K
  float*  vbuf  = (float*)(ws + 17*MB);     // 1MB f32 V
  ushort* zb    = (ushort*)(ws + 12*MB);    // 2MB bf16 z (overlaps dead qbuf)
  ushort* gb    = (ushort*)(ws + 14*MB);    // 6.3MB expert acts (overlaps dead q/k/v)
  ushort* s_gb  = (ushort*)(ws + 20*MB + 512*1024); // 1MB shared-expert act
  char*   misc  = ws + 22*MB;
  int*   sel      = (int*)(misc);
  float* topw     = (float*)(misc + 24576);
  int*   counts   = (int*)(misc + 49152);
  int*   offs     = (int*)(misc + 49408);
  int*   cursor   = (int*)(misc + 49664);
  int*   ntiles   = (int*)(misc + 50432);
  int*   tile2e   = (int*)(misc + 50688);
  int*   tile2mt  = (int*)(misc + 51200);
  int*   tok_list = (int*)(misc + 51712);
  float* wt_list  = (float*)(misc + 76288);

  // 1. attn rmsnorm
  rmsnorm_k<<<SEQ, 256, 0, stream>>>(x, anw, hx, nullptr);
  // 2. fused QKV projection (bf16 inputs, f32 outputs)
  mfma_gemm_qkv<<<dim3(12, 64), 256, 0, stream>>>(hx, wq, wk, wvv, qbuf, kbuf, vbuf);
  // 3. causal flash attention with fused q/k rmsnorm + rope -> hx
  attn_fused<<<dim3(SEQ / 64, NHEADS), 256, 0, stream>>>(qbuf, kbuf, vbuf,
      qnw, knw, fcos, fsin, hx);
  // 4. o @ wo + x -> h (split-bf16, protects gate top-k; d_out = h)
  mfma_gemm_k<<<dim3(8, 64), 256, 0, stream>>>(hx, wo, h, out, x, 1024, 1024);
  // 5. ffn rmsnorm -> z (f32) + zb (bf16)
  rmsnorm_k<<<SEQ, 256, 0, stream>>>(h, fnw, z, zb);
  // 6. gate + top-k + bucketing + flattened tile list (incl. shared tiles)
  hipMemsetAsync(counts, 0, 256, stream);
  gate_topk_k<<<SEQ, 64, 0, stream>>>(z, gatew, sel, topw, counts);
  scan_k<<<1, 64, 0, stream>>>(counts, offs, cursor, tile2e, tile2mt, ntiles);
  scatter_k<<<SEQ / 256, 256, 0, stream>>>(sel, topw, cursor, tok_list, wt_list);
  // 7. MoE phase A (experts + shared expert in one dispatch)
  moe_up6<<<dim3(HEXP / 64, MAXTILES), 256, 0, stream>>>(zb, w1e, w3e,
      (size_t)D_MODEL * HEXP, sw1, sw3, gb, s_gb, tok_list, wt_list,
      counts, offs, tile2e, tile2mt, ntiles);
  // 8. MoE phase B (experts + shared expert in one dispatch)
  moe_down6<<<dim3(D_MODEL / 128, MAXTILES), 256, 0, stream>>>(gb, s_gb, w2e,
      (size_t)HEXP * D_MODEL, sw2, out, tok_list, counts, offs,
      tile2e, tile2mt, ntiles);
  (void)in_sizes; (void)n_in; (void)out_size; (void)ws_size;
}